// Round 6
// baseline (437.542 us; speedup 1.0000x reference)
//
#include <hip/hip_runtime.h>
#include <hip/hip_bf16.h>
#include <stdint.h>

typedef unsigned short u16;
typedef __attribute__((ext_vector_type(8))) __bf16 bf16x8;
typedef __attribute__((ext_vector_type(4))) float f32x4;
typedef __attribute__((ext_vector_type(8))) u16 u16x8;
typedef __attribute__((ext_vector_type(4))) u16 u16x4;

typedef const __attribute__((address_space(1))) void GV;
typedef __attribute__((address_space(3))) void LV;

__device__ __forceinline__ u16 f2bf(float f) {
  union { float f; uint32_t u; } c; c.f = f;
  uint32_t u = c.u;
  u = u + 0x7FFFu + ((u >> 16) & 1u);
  return (u16)(u >> 16);
}

#define SBAR do { __builtin_amdgcn_sched_barrier(0); __builtin_amdgcn_s_barrier(); \
                  __builtin_amdgcn_sched_barrier(0); } while (0)
#define LGKM0 do { asm volatile("s_waitcnt lgkmcnt(0)" ::: "memory"); \
                   __builtin_amdgcn_sched_barrier(0); } while (0)

// ---------------------------------------------------------------------------
// 256x256 tile, BK=64, 8 waves (2M x 4N), 8-phase schedule (m201 template):
// per phase {ds_read subtile ; stage 1 half-tile ; bar ; lgkm0 ; 16 MFMA ; bar},
// counted vmcnt(4) at END of phases 4 and 8 (never 0 in steady state).
// st_16x32 LDS swizzle: linear dest + inverse-swizzled global source + XOR read.
// Stage slots: ph1,2 -> (T+1).B (buf1-B, last read prev ph7); ph3,4 -> (T+2).A
// (buf0-A, last read ph2); ph5,6 -> (T+2).B (buf0-B, last read ph3);
// ph7,8 -> (T+3).A (buf1-A, last read ph6).  All >=1 barrier after last read.
// MODE 0: fp32 C.  MODE 1: QKV split (+bias, bf16).  MODE 2: C = acc*scale+am+pw*pm.
// ---------------------------------------------------------------------------
template<int MODE>
__global__ __launch_bounds__(512, 2) void gemm256(
    const u16* __restrict__ A, const u16* __restrict__ B,
    int K, int lda, int ldb, long sAb, long sBb,
    float* __restrict__ Cf, int ldc, long sCb,
    u16* __restrict__ Qo, u16* __restrict__ Ko, u16* __restrict__ Vo,
    const float* __restrict__ bias,
    const float* __restrict__ am, const float* __restrict__ pm,
    const float* __restrict__ pw)
{
  const int tid  = threadIdx.x;
  const int lane = tid & 63;
  const int wid  = tid >> 6;      // 0..7
  const int wr   = wid >> 2;      // 0..1  (M)
  const int wc   = wid & 3;       // 0..3  (N)
  const int frow = lane & 15;
  const int kq   = (lane >> 4) * 8;
  const int bz   = blockIdx.z;

  // T1 XCD swizzle (nwg % 8 == 0 for all grids used here)
  const int nwg = gridDim.x * gridDim.y;
  const int wg  = blockIdx.y * gridDim.x + blockIdx.x;
  const int cpx = nwg >> 3;
  const int swg = (wg & 7) * cpx + (wg >> 3);
  const int bx  = swg % gridDim.x;
  const int by  = swg / gridDim.x;

  const u16* Ab = A + (long)bz * sAb;
  const u16* Bb = B + (long)bz * sBb;
  const int row0 = by * 256;
  const int col0 = bx * 256;

  __shared__ u16 As[2][256][64];   // 64 KB
  __shared__ u16 Bs[2][256][64];   // 64 KB

  f32x4 acc[8][4];
#pragma unroll
  for (int i = 0; i < 8; ++i)
#pragma unroll
    for (int j = 0; j < 4; ++j) acc[i][j] = (f32x4)(0.f);

  bf16x8 aR[8][2];   // both M-halves resident
  bf16x8 bR[2][2];   // one N-half at a time

  const int nkt   = K >> 6;
  const int niter = nkt >> 1;     // K multiple of 128 required (1024/2048 ok)

  const int s_rl  = wid * 8 + (lane >> 3);   // + half*128 + r*64
  const int s_ch  = (lane & 7) * 16;         // byte chunk within row

  // half-tile = 128 rows x 64 cols; 2 global_load_lds per wave (vmcnt units)
  auto STAGE = [&](const u16* Gb, int ldx, int base0, u16* lb, int half, int kt) {
#pragma unroll
    for (int r = 0; r < 2; ++r) {
      const int rl  = half * 128 + r * 64 + s_rl;
      const int sc_ = s_ch ^ ((rl & 4) << 3);               // inverse-swizzled source slot
      const u16* g  = Gb + (long)(base0 + rl) * ldx + kt * 64 + (sc_ >> 1);
      __builtin_amdgcn_global_load_lds((GV*)g,
          (LV*)((char*)lb + (half * 128 + r * 64 + wid * 8) * 128), 16, 0, 0);
    }
  };
  auto LDA4 = [&](const u16* lb, int mh) {                   // 8 ds_read_b128
#pragma unroll
    for (int m = 0; m < 4; ++m)
#pragma unroll
      for (int ks = 0; ks < 2; ++ks) {
        const int row = wr * 128 + (mh * 4 + m) * 16 + frow;
        const int lin = row * 128 + (ks * 32 + kq) * 2;
        aR[mh * 4 + m][ks] = *(const bf16x8*)((const char*)lb + (lin ^ ((row & 4) << 3)));
      }
  };
  auto LDB2 = [&](const u16* lb, int nh) {                   // 4 ds_read_b128
#pragma unroll
    for (int n = 0; n < 2; ++n)
#pragma unroll
      for (int ks = 0; ks < 2; ++ks) {
        const int row = wc * 64 + (nh * 2 + n) * 16 + frow;
        const int lin = row * 128 + (ks * 32 + kq) * 2;
        bR[n][ks] = *(const bf16x8*)((const char*)lb + (lin ^ ((row & 4) << 3)));
      }
  };
  auto MF = [&](int mh, int nh) {                            // 16 MFMA (one quadrant, K=64)
    __builtin_amdgcn_s_setprio(1);
#pragma unroll
    for (int m = 0; m < 4; ++m)
#pragma unroll
      for (int n = 0; n < 2; ++n)
#pragma unroll
        for (int ks = 0; ks < 2; ++ks)
          acc[mh * 4 + m][nh * 2 + n] = __builtin_amdgcn_mfma_f32_16x16x32_bf16(
              aR[mh * 4 + m][ks], bR[n][ks], acc[mh * 4 + m][nh * 2 + n], 0, 0, 0);
    __builtin_amdgcn_s_setprio(0);
  };

  u16* wa0 = &As[0][0][0]; u16* wa1 = &As[1][0][0];
  u16* wb0 = &Bs[0][0][0]; u16* wb1 = &Bs[1][0][0];

  // prologue: T0 fully + T1.A  (12 loads); vmcnt(4) retires all of T0
  STAGE(Ab, lda, row0, wa0, 0, 0); STAGE(Ab, lda, row0, wa0, 1, 0);
  STAGE(Bb, ldb, col0, wb0, 0, 0); STAGE(Bb, ldb, col0, wb0, 1, 0);
  if (nkt > 1) { STAGE(Ab, lda, row0, wa1, 0, 1); STAGE(Ab, lda, row0, wa1, 1, 1); }
  asm volatile("s_waitcnt vmcnt(4)" ::: "memory");
  SBAR;

  for (int i = 0; i < niter; ++i) {
    const int T = 2 * i;
    const bool lastI = (i == niter - 1);
    // ---- K-tile T (buf0) ----
    // ph1
    LDA4(wa0, 0); LDB2(wb0, 0);
    STAGE(Bb, ldb, col0, wb1, 0, T + 1);
    SBAR; LGKM0; MF(0, 0); SBAR;
    // ph2
    LDA4(wa0, 1);
    STAGE(Bb, ldb, col0, wb1, 1, T + 1);
    SBAR; LGKM0; MF(1, 0); SBAR;
    // ph3
    LDB2(wb0, 1);
    if (T + 2 < nkt) STAGE(Ab, lda, row0, wa0, 0, T + 2);
    SBAR; LGKM0; MF(0, 1); SBAR;
    // ph4
    if (T + 2 < nkt) STAGE(Ab, lda, row0, wa0, 1, T + 2);
    SBAR; MF(1, 1);
    if (lastI) asm volatile("s_waitcnt vmcnt(0)" ::: "memory");
    else       asm volatile("s_waitcnt vmcnt(4)" ::: "memory");
    SBAR;
    // ---- K-tile T+1 (buf1) ----
    // ph5
    LDA4(wa1, 0); LDB2(wb1, 0);
    if (T + 2 < nkt) STAGE(Bb, ldb, col0, wb0, 0, T + 2);
    SBAR; LGKM0; MF(0, 0); SBAR;
    // ph6
    LDA4(wa1, 1);
    if (T + 2 < nkt) STAGE(Bb, ldb, col0, wb0, 1, T + 2);
    SBAR; LGKM0; MF(1, 0); SBAR;
    // ph7
    LDB2(wb1, 1);
    if (T + 3 < nkt) STAGE(Ab, lda, row0, wa1, 0, T + 3);
    SBAR; LGKM0; MF(0, 1); SBAR;
    // ph8
    if (T + 3 < nkt) STAGE(Ab, lda, row0, wa1, 1, T + 3);
    SBAR; MF(1, 1);
    if (!lastI) asm volatile("s_waitcnt vmcnt(4)" ::: "memory");
    SBAR;
  }

  // epilogue
  const int cr = (lane >> 4) * 4;
  const int cc = lane & 15;
  const float wgt = (MODE == 2) ? pw[0] : 0.f;
#pragma unroll
  for (int mf = 0; mf < 8; ++mf) {
#pragma unroll
    for (int nf = 0; nf < 4; ++nf) {
      const int gcol = col0 + wc * 64 + nf * 16 + cc;
#pragma unroll
      for (int r = 0; r < 4; ++r) {
        const int grow = row0 + wr * 128 + mf * 16 + cr + r;
        float v = acc[mf][nf][r];
        if (MODE == 0) {
          Cf[(long)bz * sCb + (long)grow * ldc + gcol] = v;
        } else if (MODE == 2) {
          const long idx = (long)bz * sCb + (long)grow * ldc + gcol;
          Cf[idx] = fmaf(v, 0.03125f, fmaf(wgt, pm[idx], am[idx]));
        } else {
          v += bias[gcol];
          u16 h = f2bf(v);
          if (gcol < 1024)      Qo[(long)grow * 1024 + gcol] = h;
          else if (gcol < 2048) Ko[(long)grow * 1024 + (gcol - 1024)] = h;
          else                  Vo[(long)grow * 1024 + (gcol - 2048)] = h;
        }
      }
    }
  }
}

// fused: X=bf16(hs), Wqkv=bf16(Wq|Wk|Wv), bias=bq|bk|bv  (one launch)
__global__ __launch_bounds__(256) void prep_all(
    const float* __restrict__ hs, const float* __restrict__ Wq,
    const float* __restrict__ Wk, const float* __restrict__ Wv,
    const float* __restrict__ bq, const float* __restrict__ bk,
    const float* __restrict__ bv,
    u16* __restrict__ X, u16* __restrict__ Wqkv, float* __restrict__ bias)
{
  const long t = (long)blockIdx.x * 256 + threadIdx.x;   // 11264*256 = 2,883,584
  const float* src; u16* dst; long i4;
  if (t < 2097152L)       { src = hs; dst = X;              i4 = t; }
  else if (t < 2359296L)  { src = Wq; dst = Wqkv;           i4 = t - 2097152L; }
  else if (t < 2621440L)  { src = Wk; dst = Wqkv + 1048576; i4 = t - 2359296L; }
  else                    { src = Wv; dst = Wqkv + 2097152; i4 = t - 2621440L; }
  const long e = i4 * 4;
  float4 v = *(const float4*)(src + e);
  u16x4 rr; rr[0] = f2bf(v.x); rr[1] = f2bf(v.y); rr[2] = f2bf(v.z); rr[3] = f2bf(v.w);
  *(u16x4*)(dst + e) = rr;
  if (t < 3072) bias[t] = (t < 1024) ? bq[t] : (t < 2048) ? bk[t - 1024] : bv[t - 2048];
}

// V [B][2048][1024] bf16 -> Vt [B][1024][2048]
__global__ __launch_bounds__(256) void transpose_bf16(const u16* __restrict__ V,
                                                      u16* __restrict__ Vt)
{
  __shared__ u16 t[32][33];
  const int b = blockIdx.z;
  const u16* Vb = V + (long)b * 2097152;
  u16* Vtb = Vt + (long)b * 2097152;
  const int tx = threadIdx.x & 31, ty = threadIdx.x >> 5;
  const int h0 = blockIdx.x * 32, s0 = blockIdx.y * 32;
#pragma unroll
  for (int i = 0; i < 4; ++i)
    t[ty + i * 8][tx] = Vb[(long)(s0 + ty + i * 8) * 1024 + h0 + tx];
  __syncthreads();
#pragma unroll
  for (int i = 0; i < 4; ++i)
    Vtb[(long)(h0 + ty + i * 8) * 2048 + s0 + tx] = t[tx][ty + i * 8];
}

// softmax over pre-biased scores (masks fused in gemm256<2>); P compact bf16
__global__ __launch_bounds__(256) void softmax_rows(
    const float* __restrict__ scores, u16* __restrict__ P)
{
  const long g = blockIdx.x;
  const int tid = threadIdx.x;
  const int lane = tid & 63;
  const int wv = tid >> 6;
  const float* s = scores + g * 2048;
  u16* po = P + g * 2048;

  float v[8];
  *(float4*)&v[0] = *(const float4*)(s + tid * 8);
  *(float4*)&v[4] = *(const float4*)(s + tid * 8 + 4);

  float mx = -3.0e38f;
#pragma unroll
  for (int i = 0; i < 8; ++i) mx = fmaxf(mx, v[i]);
#pragma unroll
  for (int off = 32; off >= 1; off >>= 1) mx = fmaxf(mx, __shfl_xor(mx, off, 64));
  __shared__ float rmax[4], rsum[4];
  if (lane == 0) rmax[wv] = mx;
  __syncthreads();
  mx = fmaxf(fmaxf(rmax[0], rmax[1]), fmaxf(rmax[2], rmax[3]));

  float sum = 0.f;
#pragma unroll
  for (int i = 0; i < 8; ++i) { v[i] = __expf(v[i] - mx); sum += v[i]; }
#pragma unroll
  for (int off = 32; off >= 1; off >>= 1) sum += __shfl_xor(sum, off, 64);
  if (lane == 0) rsum[wv] = sum;
  __syncthreads();
  sum = rsum[0] + rsum[1] + rsum[2] + rsum[3];
  const float inv = 1.0f / sum;

  u16x8 o;
#pragma unroll
  for (int i = 0; i < 8; ++i) o[i] = f2bf(v[i] * inv);
  *(u16x8*)(po + tid * 8) = o;
}

extern "C" void kernel_launch(void* const* d_in, const int* in_sizes, int n_in,
                              void* d_out, int out_size, void* d_ws, size_t ws_size,
                              hipStream_t stream) {
  const float* hs = (const float*)d_in[0];
  const float* am = (const float*)d_in[1];
  const float* pm = (const float*)d_in[2];
  const float* Wq = (const float*)d_in[3];
  const float* bq = (const float*)d_in[4];
  const float* Wk = (const float*)d_in[5];
  const float* bk = (const float*)d_in[6];
  const float* Wv = (const float*)d_in[7];
  const float* bv = (const float*)d_in[8];
  const float* pw = (const float*)d_in[9];
  float* out = (float*)d_out;

  char* w = (char*)d_ws;
  u16* X      = (u16*)(w);                    // 16,777,216 B (reused as Vt)
  u16* Wqkv   = (u16*)(w + 16777216);         //  6,291,456 B
  float* bias = (float*)(w + 23068672);       //     16,384 B
  u16* Qb     = (u16*)(w + 23085056);         // 16,777,216 B
  u16* Kb     = (u16*)(w + 39862272);         // 16,777,216 B
  u16* Vb     = (u16*)(w + 56639488);         // 16,777,216 B
  float* sc   = (float*)(w + 73416704);       // 67,108,864 B
  u16* Vt     = X;                            // X dead after GEMM1
  u16* Pc     = Qb;                           // P compact (33.5 MB over Qb+Kb, dead after GEMM2)

  // converts + bias (one launch)
  hipLaunchKernelGGL(prep_all, dim3(11264), dim3(256), 0, stream,
                     hs, Wq, Wk, Wv, bq, bk, bv, X, Wqkv, bias);

  // GEMM1: X[8192,1024] @ Wqkv[3072,1024]^T -> Q,K,V bf16 (split +bias)
  hipLaunchKernelGGL((gemm256<1>), dim3(12, 32, 1), dim3(512), 0, stream,
                     X, Wqkv, 1024, 1024, 1024, 0L, 0L,
                     (float*)nullptr, 0, 0L, Qb, Kb, Vb, bias,
                     (const float*)nullptr, (const float*)nullptr, (const float*)nullptr);

  // V -> Vt
  hipLaunchKernelGGL(transpose_bf16, dim3(32, 64, 4), dim3(256), 0, stream, Vb, Vt);

  // GEMM2: sc[b] = Q[b]@K[b]^T * scale + am + pw*pm  (fp32)
  hipLaunchKernelGGL((gemm256<2>), dim3(8, 8, 4), dim3(512), 0, stream,
                     Qb, Kb, 1024, 1024, 1024, 2097152L, 2097152L,
                     sc, 2048, 4194304L,
                     (u16*)nullptr, (u16*)nullptr, (u16*)nullptr, (const float*)nullptr,
                     am, pm, pw);

  // softmax; P compact bf16 into dead Qb/Kb
  hipLaunchKernelGGL(softmax_rows, dim3(8192), dim3(256), 0, stream, sc, Pc);

  // GEMM3: out[b] = P[b] @ Vt[b]^T  (fp32)
  hipLaunchKernelGGL((gemm256<0>), dim3(4, 8, 4), dim3(512), 0, stream,
                     Pc, Vt, 2048, 2048, 2048, 4194304L, 2097152L,
                     out, 1024, 2097152L,
                     (u16*)nullptr, (u16*)nullptr, (u16*)nullptr, (const float*)nullptr,
                     (const float*)nullptr, (const float*)nullptr, (const float*)nullptr);
}